// Round 8
// baseline (108.652 us; speedup 1.0000x reference)
//
#include <hip/hip_runtime.h>
#include <cstdint>
#include <cstddef>

// ============================ DIAGNOSTIC ROUND ==============================
// Work-replication to force per-kernel rocprof visibility above the ~45us
// harness poison-fills: prep x16, gemm K-loop x4 (acc scaled 0.25), fc x1.
// dur_us is deliberately inflated; revert factors to 1 next round.
// ===========================================================================
#define PREP_REP 16
#define GEMM_REP 4

#define SEQD 20
#define HID  512
#define LSEQ 2048
#define MROWS 8192
#define GBM 128
#define GBN 128
#define GBK 64
#define ITILE 8
#define ACC_FLOATS (6 * MROWS + MROWS)   // acc6[8192][6] + cjacc[8192]

typedef __attribute__((ext_vector_type(4))) float f32x4;
typedef __attribute__((ext_vector_type(8))) short bf16x8;

__device__ __forceinline__ ushort f2bf(float f) {
  union { float f; unsigned u; } v; v.f = f;
  unsigned r = v.u + 0x7fffu + ((v.u >> 16) & 1u);   // RNE
  return (ushort)(r >> 16);
}
__device__ __forceinline__ int swzb(int row, int b) {
  return (b & 0x0F) | ((b ^ ((row & 7) << 4)) & 0x70);
}
__device__ __forceinline__ void async16(const ushort* g, ushort* l) {
  __builtin_amdgcn_global_load_lds(
      (const __attribute__((address_space(1))) unsigned*)g,
      (__attribute__((address_space(3))) unsigned*)l, 16, 0, 0);
}

// ---------------------------------------------------------------------------
// Kernel 1 (prep), body x PREP_REP (idempotent).
// ---------------------------------------------------------------------------
__global__ __launch_bounds__(256) void k_prep(const float* __restrict__ X,
                                              const float* __restrict__ W1,
                                              const float* __restrict__ b1,
                                              const float* __restrict__ W2,
                                              ushort* __restrict__ h1,
                                              ushort* __restrict__ W2t,
                                              float* __restrict__ accws) {
  __shared__ float Xs[16][SEQD + 1];
  __shared__ float tile[32][33];
  const int t = threadIdx.x;
  if (blockIdx.x < 512) {
    const int base = blockIdx.x * 16;
#pragma unroll 1
    for (int rep = 0; rep < PREP_REP; ++rep) {
      for (int i = t; i < 16 * SEQD; i += 256) Xs[i / SEQD][i % SEQD] = X[base * SEQD + i];
      __syncthreads();
      const int m0 = (t >> 6) * 4;
      const int nl = (t & 63) * 4;
      float4 acc[4][2];
#pragma unroll
      for (int mi = 0; mi < 4; ++mi) {
        acc[mi][0] = *(const float4*)&b1[nl];
        acc[mi][1] = *(const float4*)&b1[nl + 256];
      }
#pragma unroll
      for (int k = 0; k < SEQD; ++k) {
        const float4 w0 = *(const float4*)&W1[k * HID + nl];
        const float4 w1 = *(const float4*)&W1[k * HID + nl + 256];
#pragma unroll
        for (int mi = 0; mi < 4; ++mi) {
          const float xv = Xs[m0 + mi][k];
          acc[mi][0].x += xv * w0.x; acc[mi][0].y += xv * w0.y;
          acc[mi][0].z += xv * w0.z; acc[mi][0].w += xv * w0.w;
          acc[mi][1].x += xv * w1.x; acc[mi][1].y += xv * w1.y;
          acc[mi][1].z += xv * w1.z; acc[mi][1].w += xv * w1.w;
        }
      }
#pragma unroll
      for (int mi = 0; mi < 4; ++mi) {
        const int m = base + m0 + mi;
#pragma unroll
        for (int g = 0; g < 2; ++g) {
          const float4 r = acc[mi][g];
          ushort4 o;
          o.x = f2bf(fmaxf(r.x, 0.f)); o.y = f2bf(fmaxf(r.y, 0.f));
          o.z = f2bf(fmaxf(r.z, 0.f)); o.w = f2bf(fmaxf(r.w, 0.f));
          const int k = nl + g * 256;
          const int sb = swzb(m, (k & 63) * 2);
          *(ushort4*)&h1[(size_t)m * HID + (k & ~63) + (sb >> 1)] = o;
        }
      }
      __syncthreads();
    }
  } else {
    const int zi = (blockIdx.x - 512) * 256 + t;
    const int c = blockIdx.x - 512;
    const int k0 = (c & 15) * 32, n0 = (c >> 4) * 32;
    const int tx = t & 31, ty = t >> 5;
#pragma unroll 1
    for (int rep = 0; rep < PREP_REP; ++rep) {
      if (zi < ACC_FLOATS) accws[zi] = 0.f;
#pragma unroll
      for (int r = ty; r < 32; r += 8)
        tile[r][tx] = W2[(size_t)(k0 + r) * HID + n0 + tx];
      __syncthreads();
#pragma unroll
      for (int r = ty; r < 32; r += 8) {
        const int n = n0 + r, k = k0 + tx;
        const int sb = swzb(n, (k & 63) * 2);
        W2t[(size_t)n * HID + (k & ~63) + (sb >> 1)] = f2bf(tile[tx][r]);
      }
      __syncthreads();
    }
  }
}

// ---------------------------------------------------------------------------
// Kernel 2: gemm2 + fused heads (R4/R7 config). K-loop x GEMM_REP; acc
// accumulates GEMM_REP copies of C and the epilogue scales by 1/GEMM_REP.
// ---------------------------------------------------------------------------
__global__ __launch_bounds__(256) void k_gemm_heads(const ushort* __restrict__ Aglob,
                                                    const ushort* __restrict__ Bglob,
                                                    const float* __restrict__ b2,
                                                    const float* __restrict__ Wss,
                                                    const float* __restrict__ Wang,
                                                    const float* __restrict__ Wc,
                                                    float* __restrict__ acc6,
                                                    float* __restrict__ cjacc) {
  __shared__ ushort As[2][GBM * GBK];
  __shared__ ushort Bs[2][GBM * GBK];
  __shared__ float  comb[2][GBM][8];
  const int t = threadIdx.x;
  const int wave = t >> 6, lane = t & 63;
  const int l15 = lane & 15, lhi = lane >> 4;
  const int wr = wave >> 1, wc = wave & 1;
  const int swz = (blockIdx.x & 7) * 32 + (blockIdx.x >> 3);
  const int xblk = swz & 3, yblk = swz >> 2;
  const int bm = yblk * GBM, bn = xblk * GBN;
  const int srow = lane >> 3;
  const int scol = (lane & 7) * 8;

  f32x4 acc[4][4];
#pragma unroll
  for (int mi = 0; mi < 4; ++mi)
#pragma unroll
    for (int ni = 0; ni < 4; ++ni) acc[mi][ni] = {0.f, 0.f, 0.f, 0.f};

#define STAGE(buf, k0)                                                         \
  {                                                                            \
    _Pragma("unroll")                                                          \
    for (int rd = 0; rd < 4; ++rd) {                                           \
      const int r = rd * 32 + wave * 8 + srow;                                 \
      const int lo = rd * 2048 + wave * 512;                                   \
      async16(Aglob + (size_t)(bm + r) * HID + (k0) + scol, &As[buf][lo]);     \
      async16(Bglob + (size_t)(bn + r) * HID + (k0) + scol, &Bs[buf][lo]);     \
    }                                                                          \
  }

#define COMPUTE(buf)                                                           \
  {                                                                            \
    _Pragma("unroll")                                                          \
    for (int kk = 0; kk < 2; ++kk) {                                           \
      bf16x8 af[4], bff[4];                                                    \
      _Pragma("unroll")                                                        \
      for (int mi = 0; mi < 4; ++mi) {                                         \
        const int row = wr * 64 + mi * 16 + l15;                               \
        af[mi] = *(const bf16x8*)&As[buf][(row * 128 + swzb(row, kk * 64 + lhi * 16)) >> 1]; \
      }                                                                        \
      _Pragma("unroll")                                                        \
      for (int ni = 0; ni < 4; ++ni) {                                         \
        const int rn = wc * 64 + ni * 16 + l15;                                \
        bff[ni] = *(const bf16x8*)&Bs[buf][(rn * 128 + swzb(rn, kk * 64 + lhi * 16)) >> 1]; \
      }                                                                        \
      _Pragma("unroll")                                                        \
      for (int mi = 0; mi < 4; ++mi)                                           \
        _Pragma("unroll")                                                      \
        for (int ni = 0; ni < 4; ++ni)                                         \
          acc[mi][ni] = __builtin_amdgcn_mfma_f32_16x16x32_bf16(af[mi], bff[ni], acc[mi][ni], 0, 0, 0); \
    }                                                                          \
  }

#pragma unroll 1
  for (int rep = 0; rep < GEMM_REP; ++rep) {
    STAGE(0, 0)
    __syncthreads();
#pragma unroll
    for (int kt = 0; kt < 8; ++kt) {
      if (kt < 7) STAGE((kt + 1) & 1, (kt + 1) * GBK)
      COMPUTE(kt & 1)
      __syncthreads();
    }
  }
  const float rscale = 1.0f / (float)GEMM_REP;

  // ---- epilogue ----
  float bias[4], ws0[4], ws1[4], ws2[4], wa0[4], wa1[4], wc0[4], wc1[4];
#pragma unroll
  for (int ni = 0; ni < 4; ++ni) {
    const int col = bn + wc * 64 + ni * 16 + l15;
    bias[ni] = b2[col];
    ws0[ni] = Wss[col * 3 + 0]; ws1[ni] = Wss[col * 3 + 1]; ws2[ni] = Wss[col * 3 + 2];
    wa0[ni] = Wang[col * 2 + 0]; wa1[ni] = Wang[col * 2 + 1];
    wc0[ni] = Wc[col]; wc1[ni] = Wc[HID + col];
  }
#pragma unroll
  for (int mi = 0; mi < 4; ++mi) {
#pragma unroll
    for (int j = 0; j < 4; ++j) {
      float p0 = 0, p1 = 0, p2 = 0, p3 = 0, p4 = 0, p5 = 0, p6 = 0;
#pragma unroll
      for (int ni = 0; ni < 4; ++ni) {
        const float v = fmaxf(acc[mi][ni][j] * rscale + bias[ni], 0.f);
        p0 += v * ws0[ni]; p1 += v * ws1[ni]; p2 += v * ws2[ni];
        p3 += v * wa0[ni]; p4 += v * wa1[ni];
        p5 += v * wc0[ni]; p6 += v * wc1[ni];
      }
#pragma unroll
      for (int m = 1; m <= 8; m <<= 1) {
        p0 += __shfl_xor(p0, m); p1 += __shfl_xor(p1, m); p2 += __shfl_xor(p2, m);
        p3 += __shfl_xor(p3, m); p4 += __shfl_xor(p4, m);
        p5 += __shfl_xor(p5, m); p6 += __shfl_xor(p6, m);
      }
      if (l15 == 0) {
        const int lr = wr * 64 + mi * 16 + lhi * 4 + j;
        comb[wc][lr][0] = p0; comb[wc][lr][1] = p1; comb[wc][lr][2] = p2;
        comb[wc][lr][3] = p3; comb[wc][lr][4] = p4;
        comb[wc][lr][5] = p5; comb[wc][lr][6] = p6;
      }
    }
  }
  __syncthreads();
  if (t < GBM) {
    const int row = bm + t;
#pragma unroll
    for (int q = 0; q < 6; ++q)
      atomicAdd(&acc6[(size_t)row * 6 + q], comb[0][t][q] + comb[1][t][q]);
    atomicAdd(&cjacc[row], comb[0][t][6] + comb[1][t][6]);
  }
#undef STAGE
#undef COMPUTE
}

// ---------------------------------------------------------------------------
// Kernel 3: finalize + contact (unchanged; write floor ~10.5us known).
// ---------------------------------------------------------------------------
__global__ __launch_bounds__(256) void k_fc(const float* __restrict__ acc6,
                                            const float* __restrict__ cjacc,
                                            const float* __restrict__ bss,
                                            const float* __restrict__ bang,
                                            const float* __restrict__ bc,
                                            float* __restrict__ ssO,
                                            float* __restrict__ angO,
                                            float* __restrict__ contact) {
  __shared__ float cj_l[LSEQ];
  __shared__ float ci_l[ITILE];
  const int blk = blockIdx.x;
  const int b   = blk >> 8;
  const int i0  = (blk & 255) * ITILE;
  const int t   = threadIdx.x;
  const size_t rowbase = (size_t)b * LSEQ;

  {
    const float* cjb = cjacc + rowbase;
#pragma unroll
    for (int it = 0; it < 2; ++it) {
      const int j = it * 1024 + t * 4;
      *(float4*)&cj_l[j] = *(const float4*)&cjb[j];
    }
  }
  if (t < ITILE) {
    const size_t r = rowbase + i0 + t;
    const float* a = &acc6[r * 6];
    const float l0 = a[0] + bss[0], l1 = a[1] + bss[1], l2 = a[2] + bss[2];
    const float mx = fmaxf(l0, fmaxf(l1, l2));
    const float e0 = __expf(l0 - mx), e1 = __expf(l1 - mx), e2 = __expf(l2 - mx);
    const float inv = 1.f / (e0 + e1 + e2);
    ssO[r * 3 + 0] = e0 * inv;
    ssO[r * 3 + 1] = e1 * inv;
    ssO[r * 3 + 2] = e2 * inv;
    angO[r * 2 + 0] = a[3] + bang[0];
    angO[r * 2 + 1] = a[4] + bang[1];
    ci_l[t] = a[5] + bc[0];
  }
  __syncthreads();

#pragma unroll
  for (int r = 0; r < ITILE; ++r) {
    const float base = ci_l[r];
    float* orow = contact + (rowbase + i0 + r) * LSEQ;
#pragma unroll
    for (int jc = 0; jc < 2; ++jc) {
      const int j0 = jc * 1024 + t * 4;
      const float4 c4 = *(const float4*)&cj_l[j0];
      float4 o;
      o.x = 1.f / (1.f + __expf(-(base + c4.x)));
      o.y = 1.f / (1.f + __expf(-(base + c4.y)));
      o.z = 1.f / (1.f + __expf(-(base + c4.z)));
      o.w = 1.f / (1.f + __expf(-(base + c4.w)));
      *(float4*)&orow[j0] = o;
    }
  }
}

// ---------------------------------------------------------------------------
extern "C" void kernel_launch(void* const* d_in, const int* in_sizes, int n_in,
                              void* d_out, int out_size, void* d_ws, size_t ws_size,
                              hipStream_t stream) {
  const float* X    = (const float*)d_in[0];
  const float* W1   = (const float*)d_in[1];
  const float* b1   = (const float*)d_in[2];
  const float* W2   = (const float*)d_in[3];
  const float* b2   = (const float*)d_in[4];
  const float* Wss  = (const float*)d_in[5];
  const float* bss  = (const float*)d_in[6];
  const float* Wang = (const float*)d_in[7];
  const float* bang = (const float*)d_in[8];
  const float* Wc   = (const float*)d_in[9];
  const float* bc   = (const float*)d_in[10];

  float* out     = (float*)d_out;
  float* ssO     = out;
  float* angO    = out + 24576;
  float* contact = out + 40960;

  ushort* h1  = (ushort*)contact;
  ushort* W2t = (ushort*)(contact + 2 * 1024 * 1024);

  float* acc6  = (float*)d_ws;
  float* cjacc = acc6 + (size_t)6 * MROWS;

  k_prep<<<768, 256, 0, stream>>>(X, W1, b1, W2, h1, W2t, acc6);
  k_gemm_heads<<<256, 256, 0, stream>>>(h1, W2t, b2, Wss, Wang, Wc, acc6, cjacc);
  k_fc<<<1024, 256, 0, stream>>>(acc6, cjacc, bss, bang, bc, ssO, angO, contact);
}